// Round 3
// baseline (370.214 us; speedup 1.0000x reference)
//
#include <hip/hip_runtime.h>
#include <cstdint>
#include <cmath>

#define BB 2
#define NN 512
#define DD 128
#define EE 64
#define HH 8
#define HSS 16
#define FFF 512
#define EPSF 1e-6f

// ---------------- Kernel A: q, k_t, v_t, qe projections (4 rows/block) ----------------
// k and v are written TRANSPOSED to [b][h][o][m] so kernel B reads them coalesced.
__global__ __launch_bounds__(256)
void qkv_kernel(const float* __restrict__ node,
                const float* __restrict__ Wq,
                const float* __restrict__ Wk,
                const float* __restrict__ Wv,
                float* __restrict__ q_g,
                float* __restrict__ k_t,
                float* __restrict__ v_t,
                float* __restrict__ qe_g) {
  int r0 = blockIdx.x * 4;        // first (b*N+n) row; 4 | N so blocks never straddle b
  int t = threadIdx.x;
  int b = r0 >> 9;                // N = 512
  int n0 = r0 & 511;
  __shared__ float nrow[4][DD];
  __shared__ float qrow[4][DD];   // scaled q, layout h*16+o

  nrow[t >> 7][t & 127] = node[(size_t)r0*DD + t];
  {
    int idx = t + 256;
    nrow[idx >> 7][idx & 127] = node[(size_t)r0*DD + idx];
  }
  __syncthreads();

  if (t < 128) {
    int h = t >> 4, o = t & 15;
    float aq[4] = {0.f,0.f,0.f,0.f}, av[4] = {0.f,0.f,0.f,0.f};
    const float* wq = Wq + h*(DD*HSS) + o;
    const float* wv = Wv + h*(DD*HSS) + o;
    for (int i = 0; i < DD; ++i) {
      float wqi = wq[i*HSS], wvi = wv[i*HSS];
      #pragma unroll
      for (int r = 0; r < 4; ++r) {
        float x = nrow[r][i];
        aq[r] += x * wqi;
        av[r] += x * wvi;
      }
    }
    #pragma unroll
    for (int r = 0; r < 4; ++r) {
      float qq = aq[r] * 0.25f;   // 1/sqrt(HS)
      q_g[(size_t)(r0+r)*128 + t] = qq;
      qrow[r][t] = qq;
    }
    float* vtp = v_t + ((size_t)(b*HH + h)*HSS + o)*NN + n0;   // n0 % 4 == 0 -> 16B aligned
    *(float4*)vtp = make_float4(av[0], av[1], av[2], av[3]);
  } else {
    int tt = t - 128, h = tt >> 4, o = tt & 15;
    float ak[4] = {0.f,0.f,0.f,0.f};
    const float* wk = Wk + h*((DD+EE)*HSS) + o;
    for (int i = 0; i < DD; ++i) {
      float wki = wk[i*HSS];
      #pragma unroll
      for (int r = 0; r < 4; ++r) ak[r] += nrow[r][i] * wki;
    }
    float* ktp = k_t + ((size_t)(b*HH + h)*HSS + o)*NN + n0;
    *(float4*)ktp = make_float4(ak[0], ak[1], ak[2], ak[3]);
  }
  __syncthreads();

  // qe[b,n,h,e] = sum_o q[b,n,h,o] * Wk_edge[h,e,o]
  for (int idx = t; idx < HH*EE; idx += 256) {
    int h = idx >> 6, e = idx & 63;
    const float* wke = Wk + (h*(DD+EE) + DD + e)*HSS;
    float w[HSS];
    #pragma unroll
    for (int o = 0; o < HSS; ++o) w[o] = wke[o];
    #pragma unroll
    for (int r = 0; r < 4; ++r) {
      float a = 0.f;
      #pragma unroll
      for (int o = 0; o < HSS; ++o) a += qrow[r][h*HSS + o] * w[o];
      qe_g[(size_t)(r0+r)*(HH*EE) + idx] = a;
    }
  }
}

// ------- Kernel B: logits(edge+node) -> softmax -> attn@V -> Wp -> LN1 -------
// one block per (b,n); thread t -> head h = t>>5, lane-in-head ml = t&31.
// edge is staged through double-buffered LDS with coalesced float4 global loads;
// LDS layout rotated (col = (j+row)&15) for even bank spread on ds_read_b128.
// k_t / v_t are read coalesced (b32, lane-consecutive m).
__global__ __launch_bounds__(256)
void attn_kernel(const float* __restrict__ node,
                 const float* __restrict__ edge,
                 const float* __restrict__ q_g,
                 const float* __restrict__ k_t,
                 const float* __restrict__ v_t,
                 const float* __restrict__ qe_g,
                 const float* __restrict__ Wp,
                 const float* __restrict__ bp,
                 const float* __restrict__ ln1_g,
                 const float* __restrict__ ln1_b,
                 float* __restrict__ x_g) {
  int bn = blockIdx.x;
  int b = bn >> 9;          // N = 512
  int t = threadIdx.x;
  int h = t >> 5, ml = t & 31;
  __shared__ float4 et[2][32][16];   // 16 KB, double-buffered edge tile (32 rows x 64 f)
  __shared__ float mh_s[HH*HSS];
  __shared__ float red[4];

  // qe[h][0..63] (16 float4) and q[h][0..15] into registers
  float4 qe_r[16];
  const float4* qep = (const float4*)(qe_g + (size_t)bn*(HH*EE) + h*EE);
  #pragma unroll
  for (int j = 0; j < 16; ++j) qe_r[j] = qep[j];
  float q_r[16];
  const float* qp = q_g + (size_t)bn*128 + h*HSS;
  #pragma unroll
  for (int o = 0; o < 16; ++o) q_r[o] = qp[o];

  const float4* e_base = (const float4*)(edge + (size_t)bn*NN*EE);
  const float* kt_base = k_t + (size_t)(b*HH + h)*HSS*NN;
  const float* vt_base = v_t + (size_t)(b*HH + h)*HSS*NN;

  // staging: thread covers float4 idx t and t+256 of each 512-float4 tile
  int ra = t >> 4,        ja = t & 15;         int ca = (ja + ra) & 15;
  int rb = (t + 256) >> 4, jb = t & 15;        int cb = (jb + rb) & 15;

  // prologue: prefetch tile 0
  float4 f0 = e_base[(size_t)(ra)*16 + ja];
  float4 f1 = e_base[(size_t)(rb)*16 + jb];

  float lg[16];
  for (int c = 0; c < 16; ++c) {
    int buf = c & 1;
    et[buf][ra][ca] = f0;
    et[buf][rb][cb] = f1;
    __syncthreads();
    if (c < 15) {                      // prefetch tile c+1 (lands before next iter's write)
      f0 = e_base[(size_t)((c+1)*32 + ra)*16 + ja];
      f1 = e_base[(size_t)((c+1)*32 + rb)*16 + jb];
    }
    int m = c*32 + ml;
    float acc = 0.f;
    #pragma unroll
    for (int j = 0; j < 16; ++j) {
      float4 e4 = et[buf][ml][(j + ml) & 15];
      acc += e4.x*qe_r[j].x + e4.y*qe_r[j].y + e4.z*qe_r[j].z + e4.w*qe_r[j].w;
    }
    const float* kp = kt_base + m;
    #pragma unroll
    for (int o = 0; o < 16; ++o) acc += q_r[o] * kp[o*NN];
    lg[c] = acc;
    // NOTE: next overwrite of et[buf] happens at iter c+2's write, separated from
    // this iter's reads by iter c+1's __syncthreads -> single barrier per iter is safe.
  }

  // softmax over the 512 m's of head h: 16 per lane x 32 lanes
  float mx = lg[0];
  #pragma unroll
  for (int c = 1; c < 16; ++c) mx = fmaxf(mx, lg[c]);
  #pragma unroll
  for (int off = 1; off < 32; off <<= 1) mx = fmaxf(mx, __shfl_xor(mx, off, 64));
  float sum = 0.f;
  #pragma unroll
  for (int c = 0; c < 16; ++c) { lg[c] = __expf(lg[c] - mx); sum += lg[c]; }
  #pragma unroll
  for (int off = 1; off < 32; off <<= 1) sum += __shfl_xor(sum, off, 64);
  float inv = 1.f / sum;

  // mh[h][o] partial sums over this lane's 16 m's (v_t reads coalesced over ml)
  float mh_acc[16];
  #pragma unroll
  for (int z = 0; z < 16; ++z) mh_acc[z] = 0.f;
  for (int c = 0; c < 16; ++c) {
    float p = lg[c] * inv;
    const float* vp = vt_base + c*32 + ml;
    #pragma unroll
    for (int o = 0; o < 16; ++o) mh_acc[o] += p * vp[o*NN];
  }
  #pragma unroll
  for (int z = 0; z < 16; ++z) {
    #pragma unroll
    for (int off = 1; off < 32; off <<= 1)
      mh_acc[z] += __shfl_xor(mh_acc[z], off, 64);
  }
  if (ml == 0) {
    #pragma unroll
    for (int z = 0; z < 16; ++z) mh_s[h*16 + z] = mh_acc[z];
  }
  __syncthreads();

  // attn_out = mh @ Wp + bp ; residual ; LN1   (threads 0..127)
  float val = 0.f;
  if (t < 128) {
    float a = bp[t];
    #pragma unroll 4
    for (int ho = 0; ho < 128; ++ho) a += mh_s[ho] * Wp[ho*128 + t];
    val = node[(size_t)bn*128 + t] + a;
    float s1 = val, s2 = val*val;
    #pragma unroll
    for (int off = 1; off < 64; off <<= 1) {
      s1 += __shfl_xor(s1, off, 64);
      s2 += __shfl_xor(s2, off, 64);
    }
    if ((t & 63) == 0) { red[(t>>6)*2] = s1; red[(t>>6)*2 + 1] = s2; }
  }
  __syncthreads();
  if (t < 128) {
    float s1 = red[0] + red[2], s2 = red[1] + red[3];
    float mu = s1 * (1.f/128.f);
    float var = s2 * (1.f/128.f) - mu*mu;
    float xh = (val - mu) * rsqrtf(var + EPSF);
    x_g[(size_t)bn*128 + t] = xh * ln1_g[t] + ln1_b[t];
  }
}

// ---------------- Kernel C: FFN + residual + LN2, 8 rows per block ----------------
__global__ __launch_bounds__(256)
void ffn_kernel(const float* __restrict__ x_g,
                const float* __restrict__ Wf1,
                const float* __restrict__ bf1,
                const float* __restrict__ Wf2,
                const float* __restrict__ bf2,
                const float* __restrict__ ln2_g,
                const float* __restrict__ ln2_b,
                float* __restrict__ out) {
  int t = threadIdx.x;
  int row0 = blockIdx.x * 8;
  __shared__ float xs[8][128];
  __shared__ float hs[8][FFF];
  __shared__ float red2[4][4][2];   // [wave][row-in-group][{s1,s2}]

  #pragma unroll
  for (int k = 0; k < 4; ++k) {
    int idx = t + k*256;
    ((float*)xs)[idx] = x_g[(size_t)row0*128 + idx];
  }
  __syncthreads();

  // FF1 + ReLU: thread owns columns j = t and t+256, 8 rows each
  float acc[8][2];
  #pragma unroll
  for (int r = 0; r < 8; ++r) { acc[r][0] = bf1[t]; acc[r][1] = bf1[t + 256]; }
  for (int i = 0; i < 128; ++i) {
    float w0 = Wf1[i*512 + t];
    float w1 = Wf1[i*512 + t + 256];
    #pragma unroll
    for (int r = 0; r < 8; ++r) {
      float xv = xs[r][i];
      acc[r][0] += xv * w0;
      acc[r][1] += xv * w1;
    }
  }
  #pragma unroll
  for (int r = 0; r < 8; ++r) {
    hs[r][t]       = fmaxf(acc[r][0], 0.f);
    hs[r][t + 256] = fmaxf(acc[r][1], 0.f);
  }
  __syncthreads();

  // FF2: thread (i = t&127, rg = t>>7) owns rows rg*4 .. rg*4+3
  int i = t & 127, rg = t >> 7;
  float o_[4];
  #pragma unroll
  for (int r = 0; r < 4; ++r) o_[r] = bf2[i];
  for (int j = 0; j < 512; ++j) {
    float w = Wf2[j*128 + i];
    #pragma unroll
    for (int r = 0; r < 4; ++r) o_[r] += hs[rg*4 + r][j] * w;
  }

  // residual + LN2 (each row spread across 2 waves)
  int w_ = t >> 6;
  float va[4], s1[4], s2[4];
  #pragma unroll
  for (int r = 0; r < 4; ++r) {
    va[r] = o_[r] + xs[rg*4 + r][i];
    s1[r] = va[r]; s2[r] = va[r]*va[r];
  }
  #pragma unroll
  for (int off = 1; off < 64; off <<= 1) {
    #pragma unroll
    for (int r = 0; r < 4; ++r) {
      s1[r] += __shfl_xor(s1[r], off, 64);
      s2[r] += __shfl_xor(s2[r], off, 64);
    }
  }
  if ((t & 63) == 0) {
    #pragma unroll
    for (int r = 0; r < 4; ++r) { red2[w_][r][0] = s1[r]; red2[w_][r][1] = s2[r]; }
  }
  __syncthreads();
  int pw = w_ ^ 1;
  #pragma unroll
  for (int r = 0; r < 4; ++r) {
    float S1 = red2[w_][r][0] + red2[pw][r][0];
    float S2 = red2[w_][r][1] + red2[pw][r][1];
    float mu = S1 * (1.f/128.f);
    float var = S2 * (1.f/128.f) - mu*mu;
    out[((size_t)row0 + rg*4 + r)*128 + i] =
        (va[r] - mu) * rsqrtf(var + EPSF) * ln2_g[i] + ln2_b[i];
  }
}

extern "C" void kernel_launch(void* const* d_in, const int* in_sizes, int n_in,
                              void* d_out, int out_size, void* d_ws, size_t ws_size,
                              hipStream_t stream) {
  const float* node  = (const float*)d_in[0];
  const float* edge  = (const float*)d_in[1];
  const float* Wq    = (const float*)d_in[2];
  const float* Wk    = (const float*)d_in[3];
  const float* Wv    = (const float*)d_in[4];
  const float* Wp    = (const float*)d_in[5];
  const float* bp    = (const float*)d_in[6];
  const float* ln1_g = (const float*)d_in[7];
  const float* ln1_b = (const float*)d_in[8];
  const float* Wf1   = (const float*)d_in[9];
  const float* bf1   = (const float*)d_in[10];
  const float* Wf2   = (const float*)d_in[11];
  const float* bf2   = (const float*)d_in[12];
  const float* ln2_g = (const float*)d_in[13];
  const float* ln2_b = (const float*)d_in[14];
  float* out = (float*)d_out;

  float* ws   = (float*)d_ws;
  float* q_g  = ws;                    // 131072 floats
  float* qe_g = ws + 131072;           // 524288
  float* k_t  = ws + 655360;           // 131072  [b][h][o][m]
  float* v_t  = ws + 786432;           // 131072  [b][h][o][m]
  float* x_g  = ws + 917504;           // 131072  (total 4 MiB)

  qkv_kernel<<<(BB*NN)/4, 256, 0, stream>>>(node, Wq, Wk, Wv, q_g, k_t, v_t, qe_g);
  attn_kernel<<<BB*NN, 256, 0, stream>>>(node, edge, q_g, k_t, v_t, qe_g,
                                         Wp, bp, ln1_g, ln1_b, x_g);
  ffn_kernel<<<(BB*NN)/8, 256, 0, stream>>>(x_g, Wf1, bf1, Wf2, bf2,
                                            ln2_g, ln2_b, out);
}

// Round 4
// 325.403 us; speedup vs baseline: 1.1377x; 1.1377x over previous
//
#include <hip/hip_runtime.h>
#include <cstdint>
#include <cmath>

#define BB 2
#define NN 512
#define DD 128
#define EE 64
#define HH 8
#define HSS 16
#define FFF 512
#define EPSF 1e-6f

// ---------------- Kernel A: q, k_t, v_t, qe projections (2 rows/block, 512 blocks) ----
// k and v are written TRANSPOSED to [b][h][o][m] so kernel B reads them coalesced.
__global__ __launch_bounds__(256)
void qkv_kernel(const float* __restrict__ node,
                const float* __restrict__ Wq,
                const float* __restrict__ Wk,
                const float* __restrict__ Wv,
                float* __restrict__ q_g,
                float* __restrict__ k_t,
                float* __restrict__ v_t,
                float* __restrict__ qe_g) {
  int r0 = blockIdx.x * 2;        // first (b*N+n) row; 2 | N so blocks never straddle b
  int t = threadIdx.x;
  int b = r0 >> 9;                // N = 512
  int n0 = r0 & 511;              // even -> float2 stores 8B aligned
  __shared__ float nrow[2][DD];
  __shared__ float qrow[2][DD];   // scaled q, layout h*16+o

  nrow[t >> 7][t & 127] = node[(size_t)r0*DD + t];
  __syncthreads();

  if (t < 128) {
    int h = t >> 4, o = t & 15;
    float aq[2] = {0.f,0.f}, av[2] = {0.f,0.f};
    const float* wq = Wq + h*(DD*HSS) + o;
    const float* wv = Wv + h*(DD*HSS) + o;
    for (int i = 0; i < DD; ++i) {
      float wqi = wq[i*HSS], wvi = wv[i*HSS];
      #pragma unroll
      for (int r = 0; r < 2; ++r) {
        float x = nrow[r][i];
        aq[r] += x * wqi;
        av[r] += x * wvi;
      }
    }
    #pragma unroll
    for (int r = 0; r < 2; ++r) {
      float qq = aq[r] * 0.25f;   // 1/sqrt(HS)
      q_g[(size_t)(r0+r)*128 + t] = qq;
      qrow[r][t] = qq;
    }
    *(float2*)(v_t + ((size_t)(b*HH + (t>>4))*HSS + (t&15))*NN + n0) =
        make_float2(av[0], av[1]);
  } else {
    int tt = t - 128, h = tt >> 4, o = tt & 15;
    float ak[2] = {0.f,0.f};
    const float* wk = Wk + h*((DD+EE)*HSS) + o;
    for (int i = 0; i < DD; ++i) {
      float wki = wk[i*HSS];
      #pragma unroll
      for (int r = 0; r < 2; ++r) ak[r] += nrow[r][i] * wki;
    }
    *(float2*)(k_t + ((size_t)(b*HH + h)*HSS + o)*NN + n0) = make_float2(ak[0], ak[1]);
  }
  __syncthreads();

  // qe[b,n,h,e] = sum_o q[b,n,h,o] * Wk_edge[h,e,o]
  for (int idx = t; idx < HH*EE; idx += 256) {
    int h = idx >> 6, e = idx & 63;
    const float* wke = Wk + (h*(DD+EE) + DD + e)*HSS;
    float w[HSS];
    #pragma unroll
    for (int o = 0; o < 16; ++o) w[o] = wke[o];
    #pragma unroll
    for (int r = 0; r < 2; ++r) {
      float a = 0.f;
      #pragma unroll
      for (int o = 0; o < 16; ++o) a += qrow[r][h*HSS + o] * w[o];
      qe_g[(size_t)(r0+r)*(HH*EE) + idx] = a;
    }
  }
}

// ------- Kernel B: logits(edge+node) -> softmax -> attn@V -> Wp -> LN1 -------
// one block per (b,n), 512 threads = 8 waves; head h = full wave (t>>6), ml = t&63.
// Each thread owns 8 m values. Edge double-buffered in LDS (rotated cols, 0 conflicts
// measured last round). k_t / v_t read coalesced (256B per wave-instr).
__global__ __launch_bounds__(512)
void attn_kernel(const float* __restrict__ node,
                 const float* __restrict__ edge,
                 const float* __restrict__ q_g,
                 const float* __restrict__ k_t,
                 const float* __restrict__ v_t,
                 const float* __restrict__ qe_g,
                 const float* __restrict__ Wp,
                 const float* __restrict__ bp,
                 const float* __restrict__ ln1_g,
                 const float* __restrict__ ln1_b,
                 float* __restrict__ x_g) {
  int bn = blockIdx.x;
  int b = bn >> 9;          // N = 512
  int t = threadIdx.x;
  int h = t >> 6, ml = t & 63;
  __shared__ float4 et[2][64][16];   // 32 KB double-buffered edge tile (64 rows x 64 f)
  __shared__ float mh_s[HH*HSS];
  __shared__ float red[4];

  // qe[h][0..63] (16 float4) and q[h][0..15] into registers
  float4 qe_r[16];
  const float4* qep = (const float4*)(qe_g + (size_t)bn*(HH*EE) + h*EE);
  #pragma unroll
  for (int j = 0; j < 16; ++j) qe_r[j] = qep[j];
  float q_r[16];
  const float* qp = q_g + (size_t)bn*128 + h*HSS;
  #pragma unroll
  for (int o = 0; o < 16; ++o) q_r[o] = qp[o];

  const float4* e_base = (const float4*)(edge + (size_t)bn*NN*EE);
  const float* kt_base = k_t + (size_t)(b*HH + h)*HSS*NN;
  const float* vt_base = v_t + (size_t)(b*HH + h)*HSS*NN;

  // staging: tile = 64 rows x 16 float4 = 1024 float4; thread covers idx t and t+512
  int ra = t >> 4,          ja = t & 15;   int ca = (ja + ra) & 15;
  int rb = (t + 512) >> 4,  jb = t & 15;   int cb = (jb + rb) & 15;

  // prologue: prefetch tile 0
  float4 f0 = e_base[(size_t)ra*16 + ja];
  float4 f1 = e_base[(size_t)rb*16 + jb];

  float lg[8];
  for (int c = 0; c < 8; ++c) {
    int buf = c & 1;
    et[buf][ra][ca] = f0;
    et[buf][rb][cb] = f1;
    __syncthreads();
    if (c < 7) {                      // prefetch tile c+1
      f0 = e_base[(size_t)((c+1)*64 + ra)*16 + ja];
      f1 = e_base[(size_t)((c+1)*64 + rb)*16 + jb];
    }
    int m = c*64 + ml;
    float acc = 0.f;
    #pragma unroll
    for (int j = 0; j < 16; ++j) {
      float4 e4 = et[buf][ml][(j + ml) & 15];
      acc += e4.x*qe_r[j].x + e4.y*qe_r[j].y + e4.z*qe_r[j].z + e4.w*qe_r[j].w;
    }
    const float* kp = kt_base + m;
    #pragma unroll
    for (int o = 0; o < 16; ++o) acc += q_r[o] * kp[o*NN];
    lg[c] = acc;
    // reads of et[buf] (iter c) and the next write to et[buf] (iter c+2) are
    // separated by iter c+1's __syncthreads (which drains lgkm) -> safe.
  }

  // softmax over the 512 m's of head h: 8 per lane x 64 lanes (one wave per head)
  float mx = lg[0];
  #pragma unroll
  for (int c = 1; c < 8; ++c) mx = fmaxf(mx, lg[c]);
  #pragma unroll
  for (int off = 1; off < 64; off <<= 1) mx = fmaxf(mx, __shfl_xor(mx, off, 64));
  float sum = 0.f;
  #pragma unroll
  for (int c = 0; c < 8; ++c) { lg[c] = __expf(lg[c] - mx); sum += lg[c]; }
  #pragma unroll
  for (int off = 1; off < 64; off <<= 1) sum += __shfl_xor(sum, off, 64);
  float inv = 1.f / sum;

  // mh[h][o] partial sums over this lane's 8 m's (v_t reads coalesced over ml)
  float mh_acc[16];
  #pragma unroll
  for (int z = 0; z < 16; ++z) mh_acc[z] = 0.f;
  for (int c = 0; c < 8; ++c) {
    float p = lg[c] * inv;
    const float* vp = vt_base + c*64 + ml;
    #pragma unroll
    for (int o = 0; o < 16; ++o) mh_acc[o] += p * vp[o*NN];
  }
  #pragma unroll
  for (int z = 0; z < 16; ++z) {
    #pragma unroll
    for (int off = 1; off < 64; off <<= 1)
      mh_acc[z] += __shfl_xor(mh_acc[z], off, 64);
  }
  if (ml == 0) {
    #pragma unroll
    for (int z = 0; z < 16; ++z) mh_s[h*16 + z] = mh_acc[z];
  }
  __syncthreads();

  // attn_out = mh @ Wp + bp ; residual ; LN1   (threads 0..127)
  float val = 0.f;
  if (t < 128) {
    float a = bp[t];
    #pragma unroll 4
    for (int ho = 0; ho < 128; ++ho) a += mh_s[ho] * Wp[ho*128 + t];
    val = node[(size_t)bn*128 + t] + a;
    float s1 = val, s2 = val*val;
    #pragma unroll
    for (int off = 1; off < 64; off <<= 1) {
      s1 += __shfl_xor(s1, off, 64);
      s2 += __shfl_xor(s2, off, 64);
    }
    if ((t & 63) == 0) { red[(t>>6)*2] = s1; red[(t>>6)*2 + 1] = s2; }
  }
  __syncthreads();
  if (t < 128) {
    float s1 = red[0] + red[2], s2 = red[1] + red[3];
    float mu = s1 * (1.f/128.f);
    float var = s2 * (1.f/128.f) - mu*mu;
    float xh = (val - mu) * rsqrtf(var + EPSF);
    x_g[(size_t)bn*128 + t] = xh * ln1_g[t] + ln1_b[t];
  }
}

// ---------------- Kernel C: FFN + residual + LN2, 2 rows/block, 512 blocks -------------
__global__ __launch_bounds__(256)
void ffn_kernel(const float* __restrict__ x_g,
                const float* __restrict__ Wf1,
                const float* __restrict__ bf1,
                const float* __restrict__ Wf2,
                const float* __restrict__ bf2,
                const float* __restrict__ ln2_g,
                const float* __restrict__ ln2_b,
                float* __restrict__ out) {
  int t = threadIdx.x;
  int row0 = blockIdx.x * 2;
  __shared__ float xs[2][128];
  __shared__ float hs[2][FFF];
  __shared__ float ps[2][2][128];   // [j-half][row][i] FF2 partials
  __shared__ float red2[4][2];      // [wave][{s1,s2}]

  ((float*)xs)[t] = x_g[(size_t)row0*128 + t];
  __syncthreads();

  // FF1 + ReLU: thread owns columns t and t+256, both rows
  float a00 = bf1[t], a01 = bf1[t + 256];
  float a10 = a00, a11 = a01;
  for (int i = 0; i < 128; ++i) {
    float w0 = Wf1[i*512 + t];
    float w1 = Wf1[i*512 + t + 256];
    float x0 = xs[0][i], x1 = xs[1][i];
    a00 += x0 * w0; a01 += x0 * w1;
    a10 += x1 * w0; a11 += x1 * w1;
  }
  hs[0][t]       = fmaxf(a00, 0.f);
  hs[0][t + 256] = fmaxf(a01, 0.f);
  hs[1][t]       = fmaxf(a10, 0.f);
  hs[1][t + 256] = fmaxf(a11, 0.f);
  __syncthreads();

  // FF2 partials: thread (i = t&127, half = t>>7) sums j in [half*256, half*256+256)
  // for BOTH rows (each Wf2 element reused 2x)
  int i = t & 127, half = t >> 7;
  float p0 = 0.f, p1 = 0.f;
  for (int j = half*256; j < half*256 + 256; ++j) {
    float w = Wf2[j*128 + i];
    p0 += hs[0][j] * w;
    p1 += hs[1][j] * w;
  }
  ps[half][0][i] = p0;
  ps[half][1][i] = p1;
  __syncthreads();

  // combine halves; thread handles row rg = t>>7 at column i
  int rg = half;
  float va = bf2[i] + ps[0][rg][i] + ps[1][rg][i] + xs[rg][i];

  // residual + LN2 (each row spread across 2 waves: row0 = waves 0,1; row1 = waves 2,3)
  int w_ = t >> 6;
  float s1 = va, s2 = va*va;
  #pragma unroll
  for (int off = 1; off < 64; off <<= 1) {
    s1 += __shfl_xor(s1, off, 64);
    s2 += __shfl_xor(s2, off, 64);
  }
  if ((t & 63) == 0) { red2[w_][0] = s1; red2[w_][1] = s2; }
  __syncthreads();
  int pw = w_ ^ 1;
  float S1 = red2[w_][0] + red2[pw][0];
  float S2 = red2[w_][1] + red2[pw][1];
  float mu = S1 * (1.f/128.f);
  float var = S2 * (1.f/128.f) - mu*mu;
  out[((size_t)row0 + rg)*128 + i] =
      (va - mu) * rsqrtf(var + EPSF) * ln2_g[i] + ln2_b[i];
}

extern "C" void kernel_launch(void* const* d_in, const int* in_sizes, int n_in,
                              void* d_out, int out_size, void* d_ws, size_t ws_size,
                              hipStream_t stream) {
  const float* node  = (const float*)d_in[0];
  const float* edge  = (const float*)d_in[1];
  const float* Wq    = (const float*)d_in[2];
  const float* Wk    = (const float*)d_in[3];
  const float* Wv    = (const float*)d_in[4];
  const float* Wp    = (const float*)d_in[5];
  const float* bp    = (const float*)d_in[6];
  const float* ln1_g = (const float*)d_in[7];
  const float* ln1_b = (const float*)d_in[8];
  const float* Wf1   = (const float*)d_in[9];
  const float* bf1   = (const float*)d_in[10];
  const float* Wf2   = (const float*)d_in[11];
  const float* bf2   = (const float*)d_in[12];
  const float* ln2_g = (const float*)d_in[13];
  const float* ln2_b = (const float*)d_in[14];
  float* out = (float*)d_out;

  float* ws   = (float*)d_ws;
  float* q_g  = ws;                    // 131072 floats
  float* qe_g = ws + 131072;           // 524288
  float* k_t  = ws + 655360;           // 131072  [b][h][o][m]
  float* v_t  = ws + 786432;           // 131072  [b][h][o][m]
  float* x_g  = ws + 917504;           // 131072  (total 4 MiB)

  qkv_kernel<<<(BB*NN)/2, 256, 0, stream>>>(node, Wq, Wk, Wv, q_g, k_t, v_t, qe_g);
  attn_kernel<<<BB*NN, 512, 0, stream>>>(node, edge, q_g, k_t, v_t, qe_g,
                                         Wp, bp, ln1_g, ln1_b, x_g);
  ffn_kernel<<<(BB*NN)/2, 256, 0, stream>>>(x_g, Wf1, bf1, Wf2, bf2,
                                            ln2_g, ln2_b, out);
}

// Round 11
// 307.490 us; speedup vs baseline: 1.2040x; 1.0583x over previous
//
#include <hip/hip_runtime.h>
#include <cstdint>
#include <cmath>

#define BB 2
#define NN 512
#define DD 128
#define EE 64
#define HH 8
#define HSS 16
#define FFF 512
#define EPSF 1e-6f

static __device__ __forceinline__ float rfl(float x) {
  return __uint_as_float(__builtin_amdgcn_readfirstlane(__float_as_uint(x)));
}

// ---------------- Kernel A: q, k_t, v_t, qe projections (2 rows/block, 512 blocks) ----
__global__ __launch_bounds__(256, 8)
void qkv_kernel(const float* __restrict__ node,
                const float* __restrict__ Wq,
                const float* __restrict__ Wk,
                const float* __restrict__ Wv,
                float* __restrict__ q_g,
                float* __restrict__ k_t,
                float* __restrict__ v_t,
                float* __restrict__ qe_g) {
  int r0 = blockIdx.x * 2;
  int t = threadIdx.x;
  int b = r0 >> 9;                // N = 512
  int n0 = r0 & 511;              // even -> float2 stores 8B aligned
  __shared__ float nrow[2][DD];
  __shared__ float qrow[2][DD];

  nrow[t >> 7][t & 127] = node[(size_t)r0*DD + t];
  __syncthreads();

  if (t < 128) {
    int h = t >> 4, o = t & 15;
    float aq[2] = {0.f,0.f}, av[2] = {0.f,0.f};
    const float* wq = Wq + h*(DD*HSS) + o;
    const float* wv = Wv + h*(DD*HSS) + o;
    #pragma unroll 8
    for (int i = 0; i < DD; ++i) {
      float wqi = wq[i*HSS], wvi = wv[i*HSS];
      #pragma unroll
      for (int r = 0; r < 2; ++r) {
        float x = nrow[r][i];
        aq[r] += x * wqi;
        av[r] += x * wvi;
      }
    }
    #pragma unroll
    for (int r = 0; r < 2; ++r) {
      float qq = aq[r] * 0.25f;   // 1/sqrt(HS)
      q_g[(size_t)(r0+r)*128 + t] = qq;
      qrow[r][t] = qq;
    }
    *(float2*)(v_t + ((size_t)(b*HH + (t>>4))*HSS + (t&15))*NN + n0) =
        make_float2(av[0], av[1]);
  } else {
    int tt = t - 128, h = tt >> 4, o = tt & 15;
    float ak[2] = {0.f,0.f};
    const float* wk = Wk + h*((DD+EE)*HSS) + o;
    #pragma unroll 8
    for (int i = 0; i < DD; ++i) {
      float wki = wk[i*HSS];
      #pragma unroll
      for (int r = 0; r < 2; ++r) ak[r] += nrow[r][i] * wki;
    }
    *(float2*)(k_t + ((size_t)(b*HH + h)*HSS + o)*NN + n0) = make_float2(ak[0], ak[1]);
  }
  __syncthreads();

  for (int idx = t; idx < HH*EE; idx += 256) {
    int h = idx >> 6, e = idx & 63;
    const float* wke = Wk + (h*(DD+EE) + DD + e)*HSS;
    float w[HSS];
    #pragma unroll
    for (int o = 0; o < 16; ++o) w[o] = wke[o];
    #pragma unroll
    for (int r = 0; r < 2; ++r) {
      float a = 0.f;
      #pragma unroll
      for (int o = 0; o < 16; ++o) a += qrow[r][h*HSS + o] * w[o];
      qe_g[(size_t)(r0+r)*(HH*EE) + idx] = a;
    }
  }
}

// ------- Kernel B: logits(edge+node) -> softmax -> attn@V -> Wp -> LN1 -------
// one block per (b,n), 512 threads = 8 waves; head h = wave (t>>6), ml = t&63.
// HOIST=true lifts the 80 wave-uniform qe/q operands to SGPRs via readfirstlane,
// targeting VGPR<=64 (8 waves/SIMD bracket). Control = round-4 profile of the
// identical no-hoist structure: 123 us, VGPR 88, occ 22%, 632 GB/s.
template<bool HOIST>
__global__ __launch_bounds__(512, 8)
void attn_kernel(int bn_base,
                 const float* __restrict__ node,
                 const float* __restrict__ edge,
                 const float* __restrict__ q_g,
                 const float* __restrict__ k_t,
                 const float* __restrict__ v_t,
                 const float* __restrict__ qe_g,
                 const float* __restrict__ Wp,
                 const float* __restrict__ bp,
                 const float* __restrict__ ln1_g,
                 const float* __restrict__ ln1_b,
                 float* __restrict__ x_g) {
  int bn = bn_base + blockIdx.x;
  int b = bn >> 9;          // N = 512
  int t = threadIdx.x;
  int h = t >> 6, ml = t & 63;
  __shared__ float4 et[2][64][16];   // 32 KB double-buffered edge tile
  __shared__ float mh_s[HH*HSS];
  __shared__ float red[4];

  // ---- qe (64) and q (16): wave-uniform; SGPR-hoisted iff HOIST ----
  float qe_s[64];
  {
    const float4* qep = (const float4*)(qe_g + (size_t)bn*(HH*EE) + h*EE);
    #pragma unroll
    for (int j = 0; j < 16; ++j) {
      float4 v4 = qep[j];
      if constexpr (HOIST) {
        qe_s[4*j+0] = rfl(v4.x); qe_s[4*j+1] = rfl(v4.y);
        qe_s[4*j+2] = rfl(v4.z); qe_s[4*j+3] = rfl(v4.w);
      } else {
        qe_s[4*j+0] = v4.x; qe_s[4*j+1] = v4.y;
        qe_s[4*j+2] = v4.z; qe_s[4*j+3] = v4.w;
      }
    }
  }
  float q_s[16];
  {
    const float* qp = q_g + (size_t)bn*128 + h*HSS;
    #pragma unroll
    for (int o = 0; o < 16; ++o) q_s[o] = HOIST ? rfl(qp[o]) : qp[o];
  }

  const float4* e_base = (const float4*)(edge + (size_t)bn*NN*EE);
  const float* kt_base = k_t + (size_t)(b*HH + h)*HSS*NN;
  const float* vt_base = v_t + (size_t)(b*HH + h)*HSS*NN;

  // staging indices: thread covers float4 idx t and t+512 of each 1024-float4 tile
  int ra = t >> 4,         ja = t & 15;   int ca = (ja + ra) & 15;
  int rb = (t + 512) >> 4;                int cb = (ja + rb) & 15;

  // issue tile-0 prefetch FIRST so it overlaps the whole k-dot pre-loop
  float4 f0 = e_base[(size_t)ra*16 + ja];
  float4 f1 = e_base[(size_t)rb*16 + ja];

  // ---- k-dot pre-loop: no barriers, 128 independent L2 loads ----
  float lg[8];
  #pragma unroll 2
  for (int c = 0; c < 8; ++c) {
    const float* kp = kt_base + c*64 + ml;
    float a = 0.f;
    #pragma unroll
    for (int o = 0; o < 16; ++o) a += q_s[o] * kp[o*NN];
    lg[c] = a;
  }

  // ---- edge loop: LDS double-buffer, one barrier per 64-row tile ----
  for (int c = 0; c < 8; ++c) {
    int buf = c & 1;
    et[buf][ra][ca] = f0;
    et[buf][rb][cb] = f1;
    __syncthreads();
    if (c < 7) {
      f0 = e_base[(size_t)((c+1)*64 + ra)*16 + ja];
      f1 = e_base[(size_t)((c+1)*64 + rb)*16 + ja];
    }
    float acc = 0.f;
    #pragma unroll
    for (int j = 0; j < 16; ++j) {
      float4 e4 = et[buf][ml][(j + ml) & 15];
      acc += e4.x*qe_s[4*j+0] + e4.y*qe_s[4*j+1] + e4.z*qe_s[4*j+2] + e4.w*qe_s[4*j+3];
    }
    lg[c] += acc;
    // read(c) vs next write to same buf (c+2) separated by barrier at c+1 -> safe
  }

  // ---- softmax over 512 m's: 8 per lane x 64 lanes (one wave per head) ----
  float mx = lg[0];
  #pragma unroll
  for (int c = 1; c < 8; ++c) mx = fmaxf(mx, lg[c]);
  #pragma unroll
  for (int off = 1; off < 64; off <<= 1) mx = fmaxf(mx, __shfl_xor(mx, off, 64));
  float sum = 0.f;
  #pragma unroll
  for (int c = 0; c < 8; ++c) { lg[c] = __expf(lg[c] - mx); sum += lg[c]; }
  #pragma unroll
  for (int off = 1; off < 64; off <<= 1) sum += __shfl_xor(sum, off, 64);
  float inv = 1.f / sum;

  // ---- PV in two 8-wide passes (keeps mh_acc at 8 VGPRs) ----
  #pragma unroll
  for (int half = 0; half < 2; ++half) {
    float mh_acc[8];
    #pragma unroll
    for (int z = 0; z < 8; ++z) mh_acc[z] = 0.f;
    for (int c = 0; c < 8; ++c) {
      float p = lg[c] * inv;
      const float* vp = vt_base + (size_t)half*8*NN + c*64 + ml;
      #pragma unroll
      for (int o = 0; o < 8; ++o) mh_acc[o] += p * vp[o*NN];
    }
    #pragma unroll
    for (int z = 0; z < 8; ++z) {
      #pragma unroll
      for (int off = 1; off < 64; off <<= 1)
        mh_acc[z] += __shfl_xor(mh_acc[z], off, 64);
    }
    if (ml == 0) {
      #pragma unroll
      for (int z = 0; z < 8; ++z) mh_s[h*16 + half*8 + z] = mh_acc[z];
    }
  }
  __syncthreads();

  // ---- attn_out = mh @ Wp + bp ; residual ; LN1 (threads 0..127) ----
  float val = 0.f;
  if (t < 128) {
    float a = bp[t];
    #pragma unroll 8
    for (int ho = 0; ho < 128; ++ho) a += mh_s[ho] * Wp[ho*128 + t];
    val = node[(size_t)bn*128 + t] + a;
    float s1 = val, s2 = val*val;
    #pragma unroll
    for (int off = 1; off < 64; off <<= 1) {
      s1 += __shfl_xor(s1, off, 64);
      s2 += __shfl_xor(s2, off, 64);
    }
    if ((t & 63) == 0) { red[(t>>6)*2] = s1; red[(t>>6)*2 + 1] = s2; }
  }
  __syncthreads();
  if (t < 128) {
    float s1 = red[0] + red[2], s2 = red[1] + red[3];
    float mu = s1 * (1.f/128.f);
    float var = s2 * (1.f/128.f) - mu*mu;
    float xh = (val - mu) * rsqrtf(var + EPSF);
    x_g[(size_t)bn*128 + t] = xh * ln1_g[t] + ln1_b[t];
  }
}

// ---------------- Kernel C: FFN + residual + LN2, 2 rows/block, 512 blocks -------------
__global__ __launch_bounds__(256, 8)
void ffn_kernel(const float* __restrict__ x_g,
                const float* __restrict__ Wf1,
                const float* __restrict__ bf1,
                const float* __restrict__ Wf2,
                const float* __restrict__ bf2,
                const float* __restrict__ ln2_g,
                const float* __restrict__ ln2_b,
                float* __restrict__ out) {
  int t = threadIdx.x;
  int row0 = blockIdx.x * 2;
  __shared__ float xs[2][128];
  __shared__ float hs[2][FFF];
  __shared__ float ps[2][2][128];
  __shared__ float red2[4][2];

  ((float*)xs)[t] = x_g[(size_t)row0*128 + t];
  __syncthreads();

  float a00 = bf1[t], a01 = bf1[t + 256];
  float a10 = a00, a11 = a01;
  #pragma unroll 8
  for (int i = 0; i < 128; ++i) {
    float w0 = Wf1[i*512 + t];
    float w1 = Wf1[i*512 + t + 256];
    float x0 = xs[0][i], x1 = xs[1][i];
    a00 += x0 * w0; a01 += x0 * w1;
    a10 += x1 * w0; a11 += x1 * w1;
  }
  hs[0][t]       = fmaxf(a00, 0.f);
  hs[0][t + 256] = fmaxf(a01, 0.f);
  hs[1][t]       = fmaxf(a10, 0.f);
  hs[1][t + 256] = fmaxf(a11, 0.f);
  __syncthreads();

  int i = t & 127, half = t >> 7;
  float p0 = 0.f, p1 = 0.f;
  #pragma unroll 8
  for (int j = half*256; j < half*256 + 256; ++j) {
    float w = Wf2[j*128 + i];
    p0 += hs[0][j] * w;
    p1 += hs[1][j] * w;
  }
  ps[half][0][i] = p0;
  ps[half][1][i] = p1;
  __syncthreads();

  int rg = half;
  float va = bf2[i] + ps[0][rg][i] + ps[1][rg][i] + xs[rg][i];

  int w_ = t >> 6;
  float s1 = va, s2 = va*va;
  #pragma unroll
  for (int off = 1; off < 64; off <<= 1) {
    s1 += __shfl_xor(s1, off, 64);
    s2 += __shfl_xor(s2, off, 64);
  }
  if ((t & 63) == 0) { red2[w_][0] = s1; red2[w_][1] = s2; }
  __syncthreads();
  int pw = w_ ^ 1;
  float S1 = red2[w_][0] + red2[pw][0];
  float S2 = red2[w_][1] + red2[pw][1];
  float mu = S1 * (1.f/128.f);
  float var = S2 * (1.f/128.f) - mu*mu;
  out[((size_t)row0 + rg)*128 + i] =
      (va - mu) * rsqrtf(var + EPSF) * ln2_g[i] + ln2_b[i];
}

extern "C" void kernel_launch(void* const* d_in, const int* in_sizes, int n_in,
                              void* d_out, int out_size, void* d_ws, size_t ws_size,
                              hipStream_t stream) {
  const float* node  = (const float*)d_in[0];
  const float* edge  = (const float*)d_in[1];
  const float* Wq    = (const float*)d_in[2];
  const float* Wk    = (const float*)d_in[3];
  const float* Wv    = (const float*)d_in[4];
  const float* Wp    = (const float*)d_in[5];
  const float* bp    = (const float*)d_in[6];
  const float* ln1_g = (const float*)d_in[7];
  const float* ln1_b = (const float*)d_in[8];
  const float* Wf1   = (const float*)d_in[9];
  const float* bf1   = (const float*)d_in[10];
  const float* Wf2   = (const float*)d_in[11];
  const float* bf2   = (const float*)d_in[12];
  const float* ln2_g = (const float*)d_in[13];
  const float* ln2_b = (const float*)d_in[14];
  float* out = (float*)d_out;

  float* ws   = (float*)d_ws;
  float* q_g  = ws;                    // 131072 floats
  float* qe_g = ws + 131072;           // 524288
  float* k_t  = ws + 655360;           // 131072  [b][h][o][m]
  float* v_t  = ws + 786432;           // 131072  [b][h][o][m]
  float* x_g  = ws + 917504;           // 131072

  qkv_kernel<<<(BB*NN)/2, 256, 0, stream>>>(node, Wq, Wk, Wv, q_g, k_t, v_t, qe_g);
  attn_kernel<true><<<BB*NN, 512, 0, stream>>>(0, node, edge, q_g, k_t, v_t, qe_g,
                                               Wp, bp, ln1_g, ln1_b, x_g);
  ffn_kernel<<<(BB*NN)/2, 256, 0, stream>>>(x_g, Wf1, bf1, Wf2, bf2,
                                            ln2_g, ln2_b, out);
}